// Round 1
// baseline (2818.993 us; speedup 1.0000x reference)
//
#include <hip/hip_runtime.h>
#include <math.h>

#define NN 1024          // nodes
#define BB 32            // batch
#define TT 12            // time steps
#define HH 64            // hidden
#define K1 65            // H+1 (cat features)
#define NCOLS (BB * K1)  // 2080 columns of the big GEMM
#define NH (NN * HH)     // 65536

// ---------------- row-sum -> d^{-1/2} ----------------
__global__ void rowsum_rsqrt(const float* __restrict__ M, float* __restrict__ ds) {
    int row = blockIdx.x;
    const float* p = M + (size_t)row * NN;
    float s = 0.f;
    for (int i = threadIdx.x; i < NN; i += blockDim.x) s += p[i];
    __shared__ float red[256];
    red[threadIdx.x] = s;
    __syncthreads();
    for (int off = 128; off; off >>= 1) {
        if (threadIdx.x < off) red[threadIdx.x] += red[threadIdx.x + off];
        __syncthreads();
    }
    if (threadIdx.x == 0) {
        float d = red[0];
        ds[row] = d > 0.f ? 1.0f / sqrtf(d) : 0.f;
    }
}

// ---------------- build all 12 A_t matrices ----------------
// A_t = (dtw_masked_t + L_spec + I)/2   (t < 11)
// A_11 = (dtw_masked_11 + I + L_adj + L_spec)/3
__global__ void build_A(const float* __restrict__ dtw, const float* __restrict__ adj,
                        const float* __restrict__ spec, const float* __restrict__ td,
                        const float* __restrict__ dsA, const float* __restrict__ dsS,
                        const int* __restrict__ sr_ptr, float* __restrict__ Aall) {
    int idx = blockIdx.x * blockDim.x + threadIdx.x;   // 1024*1024 threads
    int m = idx >> 10, n = idx & 1023;
    float sr = (float)sr_ptr[0];
    float dtw_v = dtw[idx], adj_v = adj[idx], spec_v = spec[idx], td_v = td[idx];
    float I = (m == n) ? 1.f : 0.f;
    float Lspec = I - dsS[m] * spec_v * dsS[n];
    float Ladj  = I - dsA[m] * adj_v * dsA[n];
    float tind = (float)TT - ceilf(fabsf(td_v) / sr);
    float base2 = 0.5f * (Lspec + I);
    float base3 = (Lspec + Ladj + I) * (1.f / 3.f);
    bool nz = (dtw_v != 0.f);
#pragma unroll
    for (int t = 0; t < TT; ++t) {
        bool act = nz && ((float)(t + 1) > tind);
        float a;
        if (t == TT - 1) a = base3 + (act ? dtw_v * (1.f / 3.f) : 0.f);
        else             a = base2 + (act ? dtw_v * 0.5f : 0.f);
        Aall[(size_t)t * NN * NN + idx] = a;
    }
}

// ---------------- build cat1 = [x_t | h_t]  layout [n][b*65+k] ----------------
__global__ void build_cat1(const float* __restrict__ inputs, const float* __restrict__ states,
                           int t, float* __restrict__ cat) {
    int idx = blockIdx.x * blockDim.x + threadIdx.x;
    if (idx >= NN * NCOLS) return;
    int n = idx / NCOLS;
    int c = idx - n * NCOLS;
    int b = c / K1;
    int k = c - b * K1;
    float v;
    if (k == 0) v = inputs[((size_t)b * TT + t) * NN + n];
    else        v = states[((size_t)t * BB + b) * NH + n * HH + (k - 1)];
    cat[idx] = v;
}

// ---------------- build cat2 = [x_t | sigmoid(gcn1)*h_t] ----------------
__global__ void build_cat2(const float* __restrict__ inputs, const float* __restrict__ states,
                           const float* __restrict__ gcn1, int t, float* __restrict__ cat) {
    int idx = blockIdx.x * blockDim.x + threadIdx.x;
    if (idx >= NN * NCOLS) return;
    int n = idx / NCOLS;
    int c = idx - n * NCOLS;
    int b = c / K1;
    int k = c - b * K1;
    float v;
    if (k == 0) v = inputs[((size_t)b * TT + t) * NN + n];
    else {
        int f = n * HH + (k - 1);                       // flat index < NH: r-half of gcn1
        float g = gcn1[(size_t)b * (2 * NH) + f];
        float r = 1.f / (1.f + expf(-g));
        v = r * states[((size_t)t * BB + b) * NH + f];
    }
    cat[idx] = v;
}

// ---------------- SGEMM: P[m][col] = sum_n A[m][n] * X[n][col] ----------------
#define BM 64
#define BN 64
#define BK 16
#define LDA_S 68   // padded LDS stride (68*4 bytes, 16B aligned, bank-rotating)

__global__ __launch_bounds__(256) void sgemm(const float* __restrict__ A,
                                             const float* __restrict__ X,
                                             float* __restrict__ P) {
    __shared__ float As[BK][LDA_S];   // As[k][m]
    __shared__ float Xs[BK][LDA_S];   // Xs[k][n]
    int tid = threadIdx.x;
    int tx = tid & 15, ty = tid >> 4;
    int m0 = blockIdx.y * BM, n0 = blockIdx.x * BN;

    int arow = tid >> 2;              // 0..63  (m within tile)
    int aq   = (tid & 3) << 2;        // k quad
    int xrow = tid >> 4;              // 0..15  (k within tile)
    int xq   = (tid & 15) << 2;       // n quad

    const float* Aptr = A + (size_t)(m0 + arow) * NN + aq;
    int xcol = n0 + xq;
    bool xok = xcol < NCOLS;
    const float* Xptr = X + (size_t)xrow * NCOLS + xcol;

    float4 av = *(const float4*)Aptr;
    float4 xv = xok ? *(const float4*)Xptr : make_float4(0.f, 0.f, 0.f, 0.f);

    float acc[4][4] = {};
    for (int k0 = 0;;) {
        __syncthreads();
        As[aq + 0][arow] = av.x; As[aq + 1][arow] = av.y;
        As[aq + 2][arow] = av.z; As[aq + 3][arow] = av.w;
        *(float4*)&Xs[xrow][xq] = xv;
        __syncthreads();
        k0 += BK;
        if (k0 < NN) {   // register prefetch of next tile overlaps compute
            av = *(const float4*)(Aptr + k0);
            xv = xok ? *(const float4*)(Xptr + (size_t)k0 * NCOLS)
                     : make_float4(0.f, 0.f, 0.f, 0.f);
        }
#pragma unroll
        for (int k = 0; k < BK; ++k) {
            float4 a4 = *(const float4*)&As[k][ty << 2];
            float4 b4 = *(const float4*)&Xs[k][tx << 2];
            const float ar[4] = {a4.x, a4.y, a4.z, a4.w};
            const float br[4] = {b4.x, b4.y, b4.z, b4.w};
#pragma unroll
            for (int i = 0; i < 4; ++i)
#pragma unroll
                for (int j = 0; j < 4; ++j) acc[i][j] += ar[i] * br[j];
        }
        if (k0 >= NN) break;
    }
#pragma unroll
    for (int i = 0; i < 4; ++i) {
        int row = m0 + (ty << 2) + i;
        int col = n0 + (tx << 2);
        if (col < NCOLS) {   // NCOLS%4==0 so full quad is in-bounds
            float4 o = make_float4(acc[i][0], acc[i][1], acc[i][2], acc[i][3]);
            *(float4*)(P + (size_t)row * NCOLS + col) = o;
        }
    }
}

// ---------------- stage2: gcn[b][m*KOUT+k2] += sum_k P[m][b*65+k]*W[k][k2] + bias[k2] ----
template <int KOUT>
__global__ __launch_bounds__(256) void stage2(const float* __restrict__ P,
                                              const float* __restrict__ W,
                                              const float* __restrict__ bias,
                                              float* __restrict__ gcn) {
    __shared__ float Pl[K1][36];        // transposed P row: Pl[k][b], padded stride
    __shared__ float Wl[K1 * KOUT];
    int m = blockIdx.x;
    for (int i = threadIdx.x; i < NCOLS; i += blockDim.x) {
        int b = i / K1, k = i - b * K1;
        Pl[k][b] = P[(size_t)m * NCOLS + i];
    }
    for (int i = threadIdx.x; i < K1 * KOUT; i += blockDim.x) Wl[i] = W[i];
    __syncthreads();

    int k2q = (threadIdx.x % (KOUT / 4)) << 2;   // k2 quad
    int bq  = (threadIdx.x / (KOUT / 4)) << 2;   // b quad
    float acc[4][4] = {};
#pragma unroll
    for (int k = 0; k < K1; ++k) {
        float4 p4 = *(const float4*)&Pl[k][bq];
        float4 w4 = *(const float4*)&Wl[k * KOUT + k2q];
        const float pr[4] = {p4.x, p4.y, p4.z, p4.w};
        const float wr[4] = {w4.x, w4.y, w4.z, w4.w};
#pragma unroll
        for (int i = 0; i < 4; ++i)
#pragma unroll
            for (int j = 0; j < 4; ++j) acc[i][j] += pr[i] * wr[j];
    }
    const float4 bv = *(const float4*)(bias + k2q);
    const float brr[4] = {bv.x, bv.y, bv.z, bv.w};
#pragma unroll
    for (int i = 0; i < 4; ++i) {
        float4* gp = (float4*)(gcn + (size_t)(bq + i) * NN * KOUT + (size_t)m * KOUT + k2q);
        float4 g = *gp;
        g.x += acc[i][0] + brr[0];
        g.y += acc[i][1] + brr[1];
        g.z += acc[i][2] + brr[2];
        g.w += acc[i][3] + brr[3];
        *gp = g;
    }
}

// ---------------- finalize: h_new = u*h + (1-u)*tanh(gcn2) ----------------
__global__ void finalize(const float* __restrict__ gcn1, const float* __restrict__ gcn2,
                         const float* __restrict__ states, float* __restrict__ out) {
    int idx = blockIdx.x * blockDim.x + threadIdx.x;   // B*NH
    if (idx >= BB * NH) return;
    int b = idx >> 16;
    int f = idx & (NH - 1);
    float u = 1.f / (1.f + expf(-gcn1[(size_t)b * 2 * NH + NH + f]));
    float h = states[((size_t)(TT - 1) * BB + b) * NH + f];
    float c = tanhf(gcn2[idx]);
    float o = u * h + (1.f - u) * c;
    out[idx] = o;
    out[(size_t)BB * NH + idx] = o;    // tuple (h_new, h_new): second copy
}

extern "C" void kernel_launch(void* const* d_in, const int* in_sizes, int n_in,
                              void* d_out, int out_size, void* d_ws, size_t ws_size,
                              hipStream_t stream) {
    const float* inputs = (const float*)d_in[0];
    const float* states = (const float*)d_in[1];
    const float* dtw    = (const float*)d_in[2];
    const float* adj    = (const float*)d_in[3];
    const float* spec   = (const float*)d_in[4];
    const float* td     = (const float*)d_in[5];
    const float* W1     = (const float*)d_in[6];
    const float* b1     = (const float*)d_in[7];
    const float* W2     = (const float*)d_in[8];
    const float* b2     = (const float*)d_in[9];
    const int*   sr     = (const int*)d_in[10];
    float* out = (float*)d_out;

    char* ws = (char*)d_ws;
    size_t off = 0;
    float* Aall = (float*)(ws + off); off += (size_t)TT * NN * NN * 4;      // 50.3 MB
    float* cat  = (float*)(ws + off); off += (size_t)NN * NCOLS * 4;        // 8.5 MB
    float* Pb   = (float*)(ws + off); off += (size_t)NN * NCOLS * 4;        // 8.5 MB
    float* gcn1 = (float*)(ws + off); off += (size_t)BB * NN * 128 * 4;     // 16.8 MB
    float* gcn2 = (float*)(ws + off); off += (size_t)BB * NN * 64 * 4;      // 8.4 MB
    float* dsA  = (float*)(ws + off); off += 4096;
    float* dsS  = (float*)(ws + off); off += 4096;

    rowsum_rsqrt<<<NN, 256, 0, stream>>>(adj, dsA);
    rowsum_rsqrt<<<NN, 256, 0, stream>>>(spec, dsS);
    build_A<<<(NN * NN) / 256, 256, 0, stream>>>(dtw, adj, spec, td, dsA, dsS, sr, Aall);

    hipMemsetAsync(gcn1, 0, (size_t)BB * NN * 128 * 4, stream);
    hipMemsetAsync(gcn2, 0, (size_t)BB * NN * 64 * 4, stream);

    const int catTotal = NN * NCOLS;
    dim3 gemmGrid((NCOLS + BN - 1) / BN, NN / BM);

    for (int t = 0; t < TT; ++t) {
        const float* At = Aall + (size_t)t * NN * NN;
        build_cat1<<<(catTotal + 255) / 256, 256, 0, stream>>>(inputs, states, t, cat);
        sgemm<<<gemmGrid, 256, 0, stream>>>(At, cat, Pb);
        stage2<128><<<NN, 256, 0, stream>>>(Pb, W1, b1, gcn1);
        build_cat2<<<(catTotal + 255) / 256, 256, 0, stream>>>(inputs, states, gcn1, t, cat);
        sgemm<<<gemmGrid, 256, 0, stream>>>(At, cat, Pb);
        stage2<64><<<NN, 128, 0, stream>>>(Pb, W2, b2, gcn2);
    }
    finalize<<<(BB * NH + 255) / 256, 256, 0, stream>>>(gcn1, gcn2, states, out);
}